// Round 1
// baseline (954.356 us; speedup 1.0000x reference)
//
#include <hip/hip_runtime.h>
#include <hip/hip_bf16.h>

#define NN 100000     // nodes
#define NE 400000     // edges
#define DD 128        // feature dim
#define NG 4096       // graphs
#define NL 5          // layers
#define NF 11         // in features

// ---------------- preprocessing ----------------

__global__ void deg_kernel(const int* __restrict__ ei, int* __restrict__ deg) {
    int e = blockIdx.x * 256 + threadIdx.x;
    if (e < NE) atomicAdd(&deg[ei[NE + e]], 1);
}

// block scans 1024 elements (4 per thread), writes per-block total
__global__ void scan1_kernel(const int* __restrict__ deg, int* __restrict__ off,
                             int* __restrict__ bsums) {
    __shared__ int lds[256];
    int tid = threadIdx.x, b = blockIdx.x;
    int base = b * 1024 + tid * 4;
    int v[4];
#pragma unroll
    for (int q = 0; q < 4; ++q) {
        int i = base + q;
        v[q] = (i < NN) ? deg[i] : 0;
    }
    int s = v[0] + v[1] + v[2] + v[3];
    lds[tid] = s;
    __syncthreads();
    for (int o = 1; o < 256; o <<= 1) {
        int t2 = (tid >= o) ? lds[tid - o] : 0;
        __syncthreads();
        lds[tid] += t2;
        __syncthreads();
    }
    int p = lds[tid] - s;  // exclusive prefix for this thread
#pragma unroll
    for (int q = 0; q < 4; ++q) {
        int i = base + q;
        if (i < NN) off[i] = p;
        p += v[q];
    }
    if (tid == 255) bsums[b] = lds[255];
}

__global__ void scan2_kernel(int* __restrict__ bsums, int nb) {
    __shared__ int lds[128];
    int tid = threadIdx.x;
    int v = (tid < nb) ? bsums[tid] : 0;
    lds[tid] = v;
    __syncthreads();
    for (int o = 1; o < 128; o <<= 1) {
        int t2 = (tid >= o) ? lds[tid - o] : 0;
        __syncthreads();
        lds[tid] += t2;
        __syncthreads();
    }
    if (tid < nb) bsums[tid] = lds[tid] - v;  // exclusive
}

__global__ void finish_kernel(int* __restrict__ off, const int* __restrict__ bsums,
                              const int* __restrict__ deg, float* __restrict__ dinv) {
    int i = blockIdx.x * 256 + threadIdx.x;
    if (i == 0) off[NN] = NE;
    if (i < NN) {
        off[i] += bsums[i >> 10];
        dinv[i] = rsqrtf((float)deg[i] + 2.0f);
    }
}

__global__ void fill_kernel(const int* __restrict__ ei, const int* __restrict__ off,
                            int* __restrict__ cursor, int* __restrict__ csr_src,
                            float* __restrict__ csr_norm, const float* __restrict__ dinv) {
    int e = blockIdx.x * 256 + threadIdx.x;
    if (e >= NE) return;
    int s = ei[e];
    int d = ei[NE + e];
    int pos = off[d] + atomicAdd(&cursor[d], 1);
    csr_src[pos] = s;
    csr_norm[pos] = dinv[s] * dinv[d];
}

// ---------------- expansion: h = log(x+1) @ We + be ----------------

__global__ void expand_kernel(const float* __restrict__ x, const float* __restrict__ We,
                              const float* __restrict__ be, float* __restrict__ h) {
    int t = blockIdx.x * 256 + threadIdx.x;  // t < NN*128
    int i = t >> 7, j = t & 127;
    float acc = be[j];
#pragma unroll
    for (int f = 0; f < NF; ++f) {
        acc += __logf(x[i * NF + f] + 1.0f) * We[f * DD + j];
    }
    h[t] = acc;
}

// ---------------- aggregation: g = self_norm*h + sum_e enorm*h[src] ----------------

__global__ void agg_kernel(const float* __restrict__ h, float* __restrict__ g,
                           const int* __restrict__ off, const int* __restrict__ csr_src,
                           const float* __restrict__ csr_norm,
                           const float* __restrict__ dinv) {
    int nb = blockIdx.x * 2 + (threadIdx.x >> 7);  // node
    int j = threadIdx.x & 127;
    float di = dinv[nb];
    float acc = 2.0f * di * di * h[(size_t)nb * DD + j];
    int e0 = off[nb], e1 = off[nb + 1];
    for (int e = e0; e < e1; ++e) {
        int s = csr_src[e];
        float w = csr_norm[e];
        acc += w * h[(size_t)s * DD + j];
    }
    g[(size_t)nb * DD + j] = acc;
}

// ---------------- GEMM epilogue-fused: h += relu(g @ W + b) ----------------
// block 256 threads: cg = tid&15 (16 col groups of 8 cols: c0..c0+3, c0+64..c0+67)
//                    rg = tid>>4 (16 row groups; thread rows = rg + 16*m, m=0..7)
// LDS: g-tile [128][132] (pad->4-bank spread, 16B aligned) + W double-buffered 8-row chunks
__global__ __launch_bounds__(256) void gemm_kernel(const float* __restrict__ g,
                                                   float* __restrict__ h,
                                                   const float* __restrict__ W,
                                                   const float* __restrict__ b) {
    __shared__ float gs[128 * 132];
    __shared__ float ws[2][8 * 128];
    const int tid = threadIdx.x;
    const int cg = tid & 15;
    const int rg = tid >> 4;
    const int row0 = blockIdx.x * 128;
    const int nrows = min(128, NN - row0);

    // stage g tile (zeros for OOB rows)
#pragma unroll
    for (int ch = 0; ch < 16; ++ch) {
        int li = ch * 1024 + tid * 4;
        int r = li >> 7, c = li & 127;
        float4 v = make_float4(0.f, 0.f, 0.f, 0.f);
        if (r < nrows) v = *(const float4*)(g + (size_t)(row0 + r) * DD + c);
        *(float4*)&gs[r * 132 + c] = v;
    }
    // preload W chunk 0 directly to LDS
    {
        float4 wv = *(const float4*)(W + tid * 4);
        *(float4*)&ws[0][tid * 4] = wv;
    }

    float acc[8][8];
#pragma unroll
    for (int m = 0; m < 8; ++m)
#pragma unroll
        for (int q = 0; q < 8; ++q) acc[m][q] = 0.f;

#pragma unroll 1
    for (int kc = 0; kc < 16; ++kc) {
        const int cur = kc & 1;
        float4 wnext;
        const bool have = (kc + 1 < 16);
        if (have) wnext = *(const float4*)(W + (kc + 1) * 1024 + tid * 4);
        __syncthreads();  // ws[cur] (and gs on kc==0) ready
#pragma unroll
        for (int kk = 0; kk < 8; ++kk) {
            const float* wrow = &ws[cur][kk * 128];
            float4 wlo = *(const float4*)(wrow + cg * 4);
            float4 whi = *(const float4*)(wrow + cg * 4 + 64);
            const int k = kc * 8 + kk;
#pragma unroll
            for (int m = 0; m < 8; ++m) {
                float gv = gs[(rg + (m << 4)) * 132 + k];
                acc[m][0] = fmaf(gv, wlo.x, acc[m][0]);
                acc[m][1] = fmaf(gv, wlo.y, acc[m][1]);
                acc[m][2] = fmaf(gv, wlo.z, acc[m][2]);
                acc[m][3] = fmaf(gv, wlo.w, acc[m][3]);
                acc[m][4] = fmaf(gv, whi.x, acc[m][4]);
                acc[m][5] = fmaf(gv, whi.y, acc[m][5]);
                acc[m][6] = fmaf(gv, whi.z, acc[m][6]);
                acc[m][7] = fmaf(gv, whi.w, acc[m][7]);
            }
        }
        if (have) *(float4*)&ws[cur ^ 1][tid * 4] = wnext;
    }

    // epilogue: h += relu(acc + b)
    float4 blo = *(const float4*)(b + cg * 4);
    float4 bhi = *(const float4*)(b + cg * 4 + 64);
#pragma unroll
    for (int m = 0; m < 8; ++m) {
        int r = rg + (m << 4);
        if (r < nrows) {
            size_t o = (size_t)(row0 + r) * DD + cg * 4;
            float4 hlo = *(const float4*)(h + o);
            float4 hhi = *(const float4*)(h + o + 64);
            hlo.x += fmaxf(acc[m][0] + blo.x, 0.f);
            hlo.y += fmaxf(acc[m][1] + blo.y, 0.f);
            hlo.z += fmaxf(acc[m][2] + blo.z, 0.f);
            hlo.w += fmaxf(acc[m][3] + blo.w, 0.f);
            hhi.x += fmaxf(acc[m][4] + bhi.x, 0.f);
            hhi.y += fmaxf(acc[m][5] + bhi.y, 0.f);
            hhi.z += fmaxf(acc[m][6] + bhi.z, 0.f);
            hhi.w += fmaxf(acc[m][7] + bhi.w, 0.f);
            *(float4*)(h + o) = hlo;
            *(float4*)(h + o + 64) = hhi;
        }
    }
}

// ---------------- pool: out[batch[i]] += h[i]  (batch sorted) ----------------

__global__ void pool_kernel(const float* __restrict__ h, const int* __restrict__ batch,
                            float* __restrict__ out) {
    int j = threadIdx.x;  // 128
    int n0 = blockIdx.x * 64;
    float acc = 0.f;
    int prev = -1;
    for (int n = 0; n < 64; ++n) {
        int i = n0 + n;
        if (i >= NN) break;
        int bi = batch[i];
        if (bi != prev) {
            if (prev >= 0) atomicAdd(&out[(size_t)prev * DD + j], acc);
            acc = 0.f;
            prev = bi;
        }
        acc += h[(size_t)i * DD + j];
    }
    if (prev >= 0) atomicAdd(&out[(size_t)prev * DD + j], acc);
}

// ---------------- launch ----------------

static inline size_t align_up(size_t x, size_t a) { return (x + a - 1) & ~(a - 1); }

extern "C" void kernel_launch(void* const* d_in, const int* in_sizes, int n_in,
                              void* d_out, int out_size, void* d_ws, size_t ws_size,
                              hipStream_t stream) {
    const float* x   = (const float*)d_in[0];
    const int*   ei  = (const int*)d_in[1];
    const int*   bat = (const int*)d_in[2];
    const float* We  = (const float*)d_in[4];
    const float* be  = (const float*)d_in[5];
    const float* Wg  = (const float*)d_in[6];
    const float* bg  = (const float*)d_in[7];
    float* out = (float*)d_out;

    // workspace carve-up
    char* p = (char*)d_ws;
    size_t o = 0;
    float* h = (float*)(p + o);       o = align_up(o + (size_t)NN * DD * 4, 512);
    float* g = (float*)(p + o);       o = align_up(o + (size_t)NN * DD * 4, 512);
    float* dinv = (float*)(p + o);    o = align_up(o + (size_t)NN * 4, 512);
    int* deg = (int*)(p + o);         size_t deg_off = o; o = align_up(o + (size_t)NN * 4, 512);
    int* cursor = (int*)(p + o);      o = align_up(o + (size_t)NN * 4, 512);
    int* off = (int*)(p + o);         o = align_up(o + (size_t)(NN + 1) * 4, 512);
    int* bsums = (int*)(p + o);       o = align_up(o + 512, 512);
    int* csr_src = (int*)(p + o);     o = align_up(o + (size_t)NE * 4, 512);
    float* csr_norm = (float*)(p + o); o = align_up(o + (size_t)NE * 4, 512);
    (void)deg_off; (void)ws_size; (void)in_sizes; (void)n_in; (void)out_size; (void)bat;

    const int GRID_E = (NE + 255) / 256;          // 1563
    const int GRID_SCAN1 = (NN + 1023) / 1024;    // 98
    const int GRID_N256 = (NN + 255) / 256;       // 391
    const int GRID_ND = (size_t)NN * DD / 256;    // 50000
    const int GRID_GEMM = (NN + 127) / 128;       // 782
    const int GRID_POOL = (NN + 63) / 64;         // 1563

    // zero deg + cursor (ws is poisoned 0xAA each call)
    hipMemsetAsync(deg, 0, (size_t)NN * 4, stream);
    hipMemsetAsync(cursor, 0, (size_t)NN * 4, stream);
    hipMemsetAsync(out, 0, (size_t)NG * DD * 4, stream);

    deg_kernel<<<GRID_E, 256, 0, stream>>>(ei, deg);
    scan1_kernel<<<GRID_SCAN1, 256, 0, stream>>>(deg, off, bsums);
    scan2_kernel<<<1, 128, 0, stream>>>(bsums, GRID_SCAN1);
    finish_kernel<<<GRID_N256, 256, 0, stream>>>(off, bsums, deg, dinv);
    fill_kernel<<<GRID_E, 256, 0, stream>>>(ei, off, cursor, csr_src, csr_norm, dinv);

    expand_kernel<<<GRID_ND, 256, 0, stream>>>(x, We, be, h);

    for (int l = 0; l < NL; ++l) {
        agg_kernel<<<NN / 2, 256, 0, stream>>>(h, g, off, csr_src, csr_norm, dinv);
        gemm_kernel<<<GRID_GEMM, 256, 0, stream>>>(g, h, Wg + (size_t)l * DD * DD,
                                                   bg + (size_t)l * DD);
    }

    pool_kernel<<<GRID_POOL, 128, 0, stream>>>(h, bat, out);
}

// Round 3
// 707.965 us; speedup vs baseline: 1.3480x; 1.3480x over previous
//
#include <hip/hip_runtime.h>
#include <hip/hip_bf16.h>

#define NN 100000     // nodes
#define NE 400000     // edges
#define DD 128        // feature dim
#define NG 4096       // graphs
#define NL 5          // layers
#define NF 11         // in features

// ---------------- preprocessing ----------------

__global__ void deg_kernel(const int* __restrict__ ei, int* __restrict__ deg) {
    int e = blockIdx.x * 256 + threadIdx.x;
    if (e < NE) atomicAdd(&deg[ei[NE + e]], 1);
}

// block scans 1024 elements (4 per thread), writes per-block total
__global__ void scan1_kernel(const int* __restrict__ deg, int* __restrict__ off,
                             int* __restrict__ bsums) {
    __shared__ int lds[256];
    int tid = threadIdx.x, b = blockIdx.x;
    int base = b * 1024 + tid * 4;
    int v[4];
#pragma unroll
    for (int q = 0; q < 4; ++q) {
        int i = base + q;
        v[q] = (i < NN) ? deg[i] : 0;
    }
    int s = v[0] + v[1] + v[2] + v[3];
    lds[tid] = s;
    __syncthreads();
    for (int o = 1; o < 256; o <<= 1) {
        int t2 = (tid >= o) ? lds[tid - o] : 0;
        __syncthreads();
        lds[tid] += t2;
        __syncthreads();
    }
    int p = lds[tid] - s;  // exclusive prefix for this thread
#pragma unroll
    for (int q = 0; q < 4; ++q) {
        int i = base + q;
        if (i < NN) off[i] = p;
        p += v[q];
    }
    if (tid == 255) bsums[b] = lds[255];
}

__global__ void scan2_kernel(int* __restrict__ bsums, int nb) {
    __shared__ int lds[128];
    int tid = threadIdx.x;
    int v = (tid < nb) ? bsums[tid] : 0;
    lds[tid] = v;
    __syncthreads();
    for (int o = 1; o < 128; o <<= 1) {
        int t2 = (tid >= o) ? lds[tid - o] : 0;
        __syncthreads();
        lds[tid] += t2;
        __syncthreads();
    }
    if (tid < nb) bsums[tid] = lds[tid] - v;  // exclusive
}

__global__ void finish_kernel(int* __restrict__ off, const int* __restrict__ bsums,
                              const int* __restrict__ deg, float* __restrict__ dinv) {
    int i = blockIdx.x * 256 + threadIdx.x;
    if (i == 0) off[NN] = NE;
    if (i < NN) {
        off[i] += bsums[i >> 10];
        dinv[i] = rsqrtf((float)deg[i] + 2.0f);
    }
}

// packed CSR record: .x = src index, .y = bitcast(norm)
__global__ void fill_kernel(const int* __restrict__ ei, const int* __restrict__ off,
                            int* __restrict__ cursor, int2* __restrict__ csr,
                            const float* __restrict__ dinv) {
    int e = blockIdx.x * 256 + threadIdx.x;
    if (e >= NE) return;
    int s = ei[e];
    int d = ei[NE + e];
    int pos = off[d] + atomicAdd(&cursor[d], 1);
    csr[pos] = make_int2(s, __float_as_int(dinv[s] * dinv[d]));
}

// ---------------- expansion: h = log(x+1) @ We + be ----------------

__global__ void expand_kernel(const float* __restrict__ x, const float* __restrict__ We,
                              const float* __restrict__ be, float* __restrict__ h) {
    int t = blockIdx.x * 256 + threadIdx.x;  // t < NN*128
    int i = t >> 7, j = t & 127;
    float acc = be[j];
#pragma unroll
    for (int f = 0; f < NF; ++f) {
        acc += __logf(x[i * NF + f] + 1.0f) * We[f * DD + j];
    }
    h[t] = acc;
}

// ---------------- aggregation: g = self_norm*h + sum_e enorm*h[src] ----------------
// 32 lanes per node (float4 per lane), 8 nodes per 256-block.
// 4-edge unrolled: 4 independent 16B gathers in flight per thread.

__global__ __launch_bounds__(256) void agg_kernel(const float* __restrict__ h,
                                                  float* __restrict__ g,
                                                  const int* __restrict__ off,
                                                  const int2* __restrict__ csr,
                                                  const float* __restrict__ dinv) {
    const int tid = threadIdx.x;
    const int node = blockIdx.x * 8 + (tid >> 5);
    const int jj = tid & 31;
    const float4* __restrict__ h4 = (const float4*)h;

    float di = dinv[node];
    float sn = 2.0f * di * di;
    float4 hv = h4[(size_t)node * 32 + jj];
    float4 acc = make_float4(sn * hv.x, sn * hv.y, sn * hv.z, sn * hv.w);

    int e = off[node];
    const int e1 = off[node + 1];
    for (; e + 4 <= e1; e += 4) {
        int2 p0 = csr[e], p1 = csr[e + 1], p2 = csr[e + 2], p3 = csr[e + 3];
        float4 v0 = h4[(size_t)p0.x * 32 + jj];
        float4 v1 = h4[(size_t)p1.x * 32 + jj];
        float4 v2 = h4[(size_t)p2.x * 32 + jj];
        float4 v3 = h4[(size_t)p3.x * 32 + jj];
        float w0 = __int_as_float(p0.y), w1 = __int_as_float(p1.y);
        float w2 = __int_as_float(p2.y), w3 = __int_as_float(p3.y);
        acc.x = fmaf(w0, v0.x, acc.x); acc.y = fmaf(w0, v0.y, acc.y);
        acc.z = fmaf(w0, v0.z, acc.z); acc.w = fmaf(w0, v0.w, acc.w);
        acc.x = fmaf(w1, v1.x, acc.x); acc.y = fmaf(w1, v1.y, acc.y);
        acc.z = fmaf(w1, v1.z, acc.z); acc.w = fmaf(w1, v1.w, acc.w);
        acc.x = fmaf(w2, v2.x, acc.x); acc.y = fmaf(w2, v2.y, acc.y);
        acc.z = fmaf(w2, v2.z, acc.z); acc.w = fmaf(w2, v2.w, acc.w);
        acc.x = fmaf(w3, v3.x, acc.x); acc.y = fmaf(w3, v3.y, acc.y);
        acc.z = fmaf(w3, v3.z, acc.z); acc.w = fmaf(w3, v3.w, acc.w);
    }
    for (; e < e1; ++e) {
        int2 p = csr[e];
        float4 v = h4[(size_t)p.x * 32 + jj];
        float w = __int_as_float(p.y);
        acc.x = fmaf(w, v.x, acc.x); acc.y = fmaf(w, v.y, acc.y);
        acc.z = fmaf(w, v.z, acc.z); acc.w = fmaf(w, v.w, acc.w);
    }
    ((float4*)g)[(size_t)node * 32 + jj] = acc;
}

// ---------------- GEMM epilogue-fused: h += relu(g @ W + b) ----------------
// block 256 threads: cg = tid&15 (16 col groups of 8 cols: c0..c0+3, c0+64..c0+67)
//                    rg = tid>>4 (16 row groups; thread rows = rg + 16*m, m=0..7)
// LDS: g-tile [128][132] (pad->4-bank spread, 16B aligned) + W double-buffered 8-row chunks
__global__ __launch_bounds__(256) void gemm_kernel(const float* __restrict__ g,
                                                   float* __restrict__ h,
                                                   const float* __restrict__ W,
                                                   const float* __restrict__ b) {
    __shared__ float gs[128 * 132];
    __shared__ float ws[2][8 * 128];
    const int tid = threadIdx.x;
    const int cg = tid & 15;
    const int rg = tid >> 4;
    const int row0 = blockIdx.x * 128;
    const int nrows = min(128, NN - row0);

    // stage g tile (zeros for OOB rows)
#pragma unroll
    for (int ch = 0; ch < 16; ++ch) {
        int li = ch * 1024 + tid * 4;
        int r = li >> 7, c = li & 127;
        float4 v = make_float4(0.f, 0.f, 0.f, 0.f);
        if (r < nrows) v = *(const float4*)(g + (size_t)(row0 + r) * DD + c);
        *(float4*)&gs[r * 132 + c] = v;
    }
    // preload W chunk 0 directly to LDS
    {
        float4 wv = *(const float4*)(W + tid * 4);
        *(float4*)&ws[0][tid * 4] = wv;
    }

    float acc[8][8];
#pragma unroll
    for (int m = 0; m < 8; ++m)
#pragma unroll
        for (int q = 0; q < 8; ++q) acc[m][q] = 0.f;

#pragma unroll 1
    for (int kc = 0; kc < 16; ++kc) {
        const int cur = kc & 1;
        float4 wnext;
        const bool have = (kc + 1 < 16);
        if (have) wnext = *(const float4*)(W + (kc + 1) * 1024 + tid * 4);
        __syncthreads();  // ws[cur] (and gs on kc==0) ready
#pragma unroll
        for (int kk = 0; kk < 8; ++kk) {
            const float* wrow = &ws[cur][kk * 128];
            float4 wlo = *(const float4*)(wrow + cg * 4);
            float4 whi = *(const float4*)(wrow + cg * 4 + 64);
            const int k = kc * 8 + kk;
#pragma unroll
            for (int m = 0; m < 8; ++m) {
                float gv = gs[(rg + (m << 4)) * 132 + k];
                acc[m][0] = fmaf(gv, wlo.x, acc[m][0]);
                acc[m][1] = fmaf(gv, wlo.y, acc[m][1]);
                acc[m][2] = fmaf(gv, wlo.z, acc[m][2]);
                acc[m][3] = fmaf(gv, wlo.w, acc[m][3]);
                acc[m][4] = fmaf(gv, whi.x, acc[m][4]);
                acc[m][5] = fmaf(gv, whi.y, acc[m][5]);
                acc[m][6] = fmaf(gv, whi.z, acc[m][6]);
                acc[m][7] = fmaf(gv, whi.w, acc[m][7]);
            }
        }
        if (have) *(float4*)&ws[cur ^ 1][tid * 4] = wnext;
    }

    // epilogue: h += relu(acc + b)
    float4 blo = *(const float4*)(b + cg * 4);
    float4 bhi = *(const float4*)(b + cg * 4 + 64);
#pragma unroll
    for (int m = 0; m < 8; ++m) {
        int r = rg + (m << 4);
        if (r < nrows) {
            size_t o = (size_t)(row0 + r) * DD + cg * 4;
            float4 hlo = *(const float4*)(h + o);
            float4 hhi = *(const float4*)(h + o + 64);
            hlo.x += fmaxf(acc[m][0] + blo.x, 0.f);
            hlo.y += fmaxf(acc[m][1] + blo.y, 0.f);
            hlo.z += fmaxf(acc[m][2] + blo.z, 0.f);
            hlo.w += fmaxf(acc[m][3] + blo.w, 0.f);
            hhi.x += fmaxf(acc[m][4] + bhi.x, 0.f);
            hhi.y += fmaxf(acc[m][5] + bhi.y, 0.f);
            hhi.z += fmaxf(acc[m][6] + bhi.z, 0.f);
            hhi.w += fmaxf(acc[m][7] + bhi.w, 0.f);
            *(float4*)(h + o) = hlo;
            *(float4*)(h + o + 64) = hhi;
        }
    }
}

// ---------------- pool: out[batch[i]] += h[i]  (batch sorted) ----------------

__global__ void pool_kernel(const float* __restrict__ h, const int* __restrict__ batch,
                            float* __restrict__ out) {
    int j = threadIdx.x;  // 128
    int n0 = blockIdx.x * 64;
    float acc = 0.f;
    int prev = -1;
    for (int n = 0; n < 64; ++n) {
        int i = n0 + n;
        if (i >= NN) break;
        int bi = batch[i];
        if (bi != prev) {
            if (prev >= 0) atomicAdd(&out[(size_t)prev * DD + j], acc);
            acc = 0.f;
            prev = bi;
        }
        acc += h[(size_t)i * DD + j];
    }
    if (prev >= 0) atomicAdd(&out[(size_t)prev * DD + j], acc);
}

// ---------------- launch ----------------

static inline size_t align_up(size_t x, size_t a) { return (x + a - 1) & ~(a - 1); }

extern "C" void kernel_launch(void* const* d_in, const int* in_sizes, int n_in,
                              void* d_out, int out_size, void* d_ws, size_t ws_size,
                              hipStream_t stream) {
    const float* x   = (const float*)d_in[0];
    const int*   ei  = (const int*)d_in[1];
    const int*   bat = (const int*)d_in[2];
    const float* We  = (const float*)d_in[4];
    const float* be  = (const float*)d_in[5];
    const float* Wg  = (const float*)d_in[6];
    const float* bg  = (const float*)d_in[7];
    float* out = (float*)d_out;

    // workspace carve-up
    char* p = (char*)d_ws;
    size_t o = 0;
    float* h = (float*)(p + o);       o = align_up(o + (size_t)NN * DD * 4, 512);
    float* g = (float*)(p + o);       o = align_up(o + (size_t)NN * DD * 4, 512);
    float* dinv = (float*)(p + o);    o = align_up(o + (size_t)NN * 4, 512);
    int* deg = (int*)(p + o);         o = align_up(o + (size_t)NN * 4, 512);
    int* cursor = (int*)(p + o);      o = align_up(o + (size_t)NN * 4, 512);
    int* off = (int*)(p + o);         o = align_up(o + (size_t)(NN + 1) * 4, 512);
    int* bsums = (int*)(p + o);       o = align_up(o + 512, 512);
    int2* csr = (int2*)(p + o);       o = align_up(o + (size_t)NE * 8, 512);
    (void)ws_size; (void)in_sizes; (void)n_in; (void)out_size;

    const int GRID_E = (NE + 255) / 256;          // 1563
    const int GRID_SCAN1 = (NN + 1023) / 1024;    // 98
    const int GRID_N256 = (NN + 255) / 256;       // 391
    const int GRID_ND = (size_t)NN * DD / 256;    // 50000
    const int GRID_GEMM = (NN + 127) / 128;       // 782
    const int GRID_POOL = (NN + 63) / 64;         // 1563
    const int GRID_AGG = NN / 8;                  // 12500

    // zero deg + cursor (ws is poisoned 0xAA each call)
    hipMemsetAsync(deg, 0, (size_t)NN * 4, stream);
    hipMemsetAsync(cursor, 0, (size_t)NN * 4, stream);
    hipMemsetAsync(out, 0, (size_t)NG * DD * 4, stream);

    deg_kernel<<<GRID_E, 256, 0, stream>>>(ei, deg);
    scan1_kernel<<<GRID_SCAN1, 256, 0, stream>>>(deg, off, bsums);
    scan2_kernel<<<1, 128, 0, stream>>>(bsums, GRID_SCAN1);
    finish_kernel<<<GRID_N256, 256, 0, stream>>>(off, bsums, deg, dinv);
    fill_kernel<<<GRID_E, 256, 0, stream>>>(ei, off, cursor, csr, dinv);

    expand_kernel<<<GRID_ND, 256, 0, stream>>>(x, We, be, h);

    for (int l = 0; l < NL; ++l) {
        agg_kernel<<<GRID_AGG, 256, 0, stream>>>(h, g, off, csr, dinv);
        gemm_kernel<<<GRID_GEMM, 256, 0, stream>>>(g, h, Wg + (size_t)l * DD * DD,
                                                   bg + (size_t)l * DD);
    }

    pool_kernel<<<GRID_POOL, 128, 0, stream>>>(h, bat, out);
}

// Round 4
// 670.521 us; speedup vs baseline: 1.4233x; 1.0558x over previous
//
#include <hip/hip_runtime.h>
#include <hip/hip_bf16.h>

#define NN 100000     // nodes
#define NE 400000     // edges
#define DD 128        // feature dim
#define NG 4096       // graphs
#define NL 5          // layers
#define NF 11         // in features

// ---------------- preprocessing ----------------

__global__ void deg_kernel(const int* __restrict__ ei, int* __restrict__ deg) {
    int e = blockIdx.x * 256 + threadIdx.x;
    if (e < NE) atomicAdd(&deg[ei[NE + e]], 1);
}

// block scans 1024 elements (4 per thread), writes per-block total
__global__ void scan1_kernel(const int* __restrict__ deg, int* __restrict__ off,
                             int* __restrict__ bsums) {
    __shared__ int lds[256];
    int tid = threadIdx.x, b = blockIdx.x;
    int base = b * 1024 + tid * 4;
    int v[4];
#pragma unroll
    for (int q = 0; q < 4; ++q) {
        int i = base + q;
        v[q] = (i < NN) ? deg[i] : 0;
    }
    int s = v[0] + v[1] + v[2] + v[3];
    lds[tid] = s;
    __syncthreads();
    for (int o = 1; o < 256; o <<= 1) {
        int t2 = (tid >= o) ? lds[tid - o] : 0;
        __syncthreads();
        lds[tid] += t2;
        __syncthreads();
    }
    int p = lds[tid] - s;  // exclusive prefix for this thread
#pragma unroll
    for (int q = 0; q < 4; ++q) {
        int i = base + q;
        if (i < NN) off[i] = p;
        p += v[q];
    }
    if (tid == 255) bsums[b] = lds[255];
}

__global__ void scan2_kernel(int* __restrict__ bsums, int nb) {
    __shared__ int lds[128];
    int tid = threadIdx.x;
    int v = (tid < nb) ? bsums[tid] : 0;
    lds[tid] = v;
    __syncthreads();
    for (int o = 1; o < 128; o <<= 1) {
        int t2 = (tid >= o) ? lds[tid - o] : 0;
        __syncthreads();
        lds[tid] += t2;
        __syncthreads();
    }
    if (tid < nb) bsums[tid] = lds[tid] - v;  // exclusive
}

__global__ void finish_kernel(int* __restrict__ off, const int* __restrict__ bsums,
                              const int* __restrict__ deg, float* __restrict__ dinv) {
    int i = blockIdx.x * 256 + threadIdx.x;
    if (i == 0) off[NN] = NE;
    if (i < NN) {
        off[i] += bsums[i >> 10];
        dinv[i] = rsqrtf((float)deg[i] + 2.0f);
    }
}

// packed CSR record: .x = src index, .y = bitcast(norm)
__global__ void fill_kernel(const int* __restrict__ ei, const int* __restrict__ off,
                            int* __restrict__ cursor, int2* __restrict__ csr,
                            const float* __restrict__ dinv) {
    int e = blockIdx.x * 256 + threadIdx.x;
    if (e >= NE) return;
    int s = ei[e];
    int d = ei[NE + e];
    int pos = off[d] + atomicAdd(&cursor[d], 1);
    csr[pos] = make_int2(s, __float_as_int(dinv[s] * dinv[d]));
}

// ---------------- expansion: h = log(x+1) @ We + be ----------------

__global__ void expand_kernel(const float* __restrict__ x, const float* __restrict__ We,
                              const float* __restrict__ be, float* __restrict__ h) {
    int t = blockIdx.x * 256 + threadIdx.x;  // t < NN*128
    int i = t >> 7, j = t & 127;
    float acc = be[j];
#pragma unroll
    for (int f = 0; f < NF; ++f) {
        acc += __logf(x[i * NF + f] + 1.0f) * We[f * DD + j];
    }
    h[t] = acc;
}

// ---------------- fused layer: hout = hin + relu((A_hat @ hin) @ W + b) ----------------
// Block = 64 nodes. Phase A: aggregate into LDS g-tile (32 lanes/node, float4/lane,
// 4-edge unrolled gathers). Phase B: register-tiled GEMM from LDS, W double-buffered.
// LDS = 64*132*4 + 2*8*128*4 = 42 KB -> 3 blocks/CU.

__global__ __launch_bounds__(256) void layer_kernel(const float* __restrict__ hin,
                                                    float* __restrict__ hout,
                                                    const int* __restrict__ off,
                                                    const int2* __restrict__ csr,
                                                    const float* __restrict__ dinv,
                                                    const float* __restrict__ W,
                                                    const float* __restrict__ b) {
    __shared__ float gs[64 * 132];
    __shared__ float ws[2][8 * 128];
    const int tid = threadIdx.x;
    const int node0 = blockIdx.x * 64;
    const float4* __restrict__ h4 = (const float4*)hin;

    // ---- Phase A: aggregate 64 nodes into gs ----
    const int jj = tid & 31;
    const int sub = tid >> 5;  // 0..7
#pragma unroll 1
    for (int p = 0; p < 8; ++p) {
        const int nl = p * 8 + sub;        // local node 0..63
        const int node = node0 + nl;
        float4 acc = make_float4(0.f, 0.f, 0.f, 0.f);
        if (node < NN) {
            float di = dinv[node];
            float sn = 2.0f * di * di;
            float4 hv = h4[(size_t)node * 32 + jj];
            acc = make_float4(sn * hv.x, sn * hv.y, sn * hv.z, sn * hv.w);
            int e = off[node];
            const int e1 = off[node + 1];
            for (; e + 4 <= e1; e += 4) {
                int2 p0 = csr[e], p1 = csr[e + 1], p2 = csr[e + 2], p3 = csr[e + 3];
                float4 v0 = h4[(size_t)p0.x * 32 + jj];
                float4 v1 = h4[(size_t)p1.x * 32 + jj];
                float4 v2 = h4[(size_t)p2.x * 32 + jj];
                float4 v3 = h4[(size_t)p3.x * 32 + jj];
                float w0 = __int_as_float(p0.y), w1 = __int_as_float(p1.y);
                float w2 = __int_as_float(p2.y), w3 = __int_as_float(p3.y);
                acc.x = fmaf(w0, v0.x, acc.x); acc.y = fmaf(w0, v0.y, acc.y);
                acc.z = fmaf(w0, v0.z, acc.z); acc.w = fmaf(w0, v0.w, acc.w);
                acc.x = fmaf(w1, v1.x, acc.x); acc.y = fmaf(w1, v1.y, acc.y);
                acc.z = fmaf(w1, v1.z, acc.z); acc.w = fmaf(w1, v1.w, acc.w);
                acc.x = fmaf(w2, v2.x, acc.x); acc.y = fmaf(w2, v2.y, acc.y);
                acc.z = fmaf(w2, v2.z, acc.z); acc.w = fmaf(w2, v2.w, acc.w);
                acc.x = fmaf(w3, v3.x, acc.x); acc.y = fmaf(w3, v3.y, acc.y);
                acc.z = fmaf(w3, v3.z, acc.z); acc.w = fmaf(w3, v3.w, acc.w);
            }
            for (; e < e1; ++e) {
                int2 pe = csr[e];
                float4 v = h4[(size_t)pe.x * 32 + jj];
                float w = __int_as_float(pe.y);
                acc.x = fmaf(w, v.x, acc.x); acc.y = fmaf(w, v.y, acc.y);
                acc.z = fmaf(w, v.z, acc.z); acc.w = fmaf(w, v.w, acc.w);
            }
        }
        *(float4*)&gs[nl * 132 + jj * 4] = acc;
    }

    // preload W chunk 0 into ws[0]
    {
        float4 wv = *(const float4*)(W + tid * 4);
        *(float4*)&ws[0][tid * 4] = wv;
    }

    // ---- Phase B: gemm gs @ W, epilogue hout = hin + relu(. + b) ----
    const int cg = tid & 15;   // col group: cols cg*4+{0..3}, cg*4+64+{0..3}
    const int rg = tid >> 4;   // row group: rows rg + 16m, m=0..3
    float acc[4][8];
#pragma unroll
    for (int m = 0; m < 4; ++m)
#pragma unroll
        for (int q = 0; q < 8; ++q) acc[m][q] = 0.f;

#pragma unroll 1
    for (int kc = 0; kc < 16; ++kc) {
        const int cur = kc & 1;
        float4 wnext;
        const bool have = (kc + 1 < 16);
        if (have) wnext = *(const float4*)(W + (kc + 1) * 1024 + tid * 4);
        __syncthreads();  // gs + ws[cur] ready
#pragma unroll
        for (int kk = 0; kk < 8; ++kk) {
            const float* wrow = &ws[cur][kk * 128];
            float4 wlo = *(const float4*)(wrow + cg * 4);
            float4 whi = *(const float4*)(wrow + cg * 4 + 64);
            const int k = kc * 8 + kk;
#pragma unroll
            for (int m = 0; m < 4; ++m) {
                float gv = gs[(rg + (m << 4)) * 132 + k];
                acc[m][0] = fmaf(gv, wlo.x, acc[m][0]);
                acc[m][1] = fmaf(gv, wlo.y, acc[m][1]);
                acc[m][2] = fmaf(gv, wlo.z, acc[m][2]);
                acc[m][3] = fmaf(gv, wlo.w, acc[m][3]);
                acc[m][4] = fmaf(gv, whi.x, acc[m][4]);
                acc[m][5] = fmaf(gv, whi.y, acc[m][5]);
                acc[m][6] = fmaf(gv, whi.z, acc[m][6]);
                acc[m][7] = fmaf(gv, whi.w, acc[m][7]);
            }
        }
        if (have) *(float4*)&ws[cur ^ 1][tid * 4] = wnext;
    }

    float4 blo = *(const float4*)(b + cg * 4);
    float4 bhi = *(const float4*)(b + cg * 4 + 64);
#pragma unroll
    for (int m = 0; m < 4; ++m) {
        int r = rg + (m << 4);
        int row = node0 + r;
        if (row < NN) {
            size_t o = (size_t)row * DD + cg * 4;
            float4 hlo = *(const float4*)(hin + o);
            float4 hhi = *(const float4*)(hin + o + 64);
            hlo.x += fmaxf(acc[m][0] + blo.x, 0.f);
            hlo.y += fmaxf(acc[m][1] + blo.y, 0.f);
            hlo.z += fmaxf(acc[m][2] + blo.z, 0.f);
            hlo.w += fmaxf(acc[m][3] + blo.w, 0.f);
            hhi.x += fmaxf(acc[m][4] + bhi.x, 0.f);
            hhi.y += fmaxf(acc[m][5] + bhi.y, 0.f);
            hhi.z += fmaxf(acc[m][6] + bhi.z, 0.f);
            hhi.w += fmaxf(acc[m][7] + bhi.w, 0.f);
            *(float4*)(hout + o) = hlo;
            *(float4*)(hout + o + 64) = hhi;
        }
    }
}

// ---------------- pool: out[batch[i]] += h[i]  (batch sorted) ----------------

__global__ void pool_kernel(const float* __restrict__ h, const int* __restrict__ batch,
                            float* __restrict__ out) {
    int j = threadIdx.x;  // 128
    int n0 = blockIdx.x * 64;
    float acc = 0.f;
    int prev = -1;
    for (int n = 0; n < 64; ++n) {
        int i = n0 + n;
        if (i >= NN) break;
        int bi = batch[i];
        if (bi != prev) {
            if (prev >= 0) atomicAdd(&out[(size_t)prev * DD + j], acc);
            acc = 0.f;
            prev = bi;
        }
        acc += h[(size_t)i * DD + j];
    }
    if (prev >= 0) atomicAdd(&out[(size_t)prev * DD + j], acc);
}

// ---------------- launch ----------------

static inline size_t align_up(size_t x, size_t a) { return (x + a - 1) & ~(a - 1); }

extern "C" void kernel_launch(void* const* d_in, const int* in_sizes, int n_in,
                              void* d_out, int out_size, void* d_ws, size_t ws_size,
                              hipStream_t stream) {
    const float* x   = (const float*)d_in[0];
    const int*   ei  = (const int*)d_in[1];
    const int*   bat = (const int*)d_in[2];
    const float* We  = (const float*)d_in[4];
    const float* be  = (const float*)d_in[5];
    const float* Wg  = (const float*)d_in[6];
    const float* bg  = (const float*)d_in[7];
    float* out = (float*)d_out;

    // workspace carve-up
    char* p = (char*)d_ws;
    size_t o = 0;
    float* h0 = (float*)(p + o);      o = align_up(o + (size_t)NN * DD * 4, 512);
    float* h1 = (float*)(p + o);      o = align_up(o + (size_t)NN * DD * 4, 512);
    float* dinv = (float*)(p + o);    o = align_up(o + (size_t)NN * 4, 512);
    int* deg = (int*)(p + o);         o = align_up(o + (size_t)NN * 4, 512);
    int* cursor = (int*)(p + o);      o = align_up(o + (size_t)NN * 4, 512);
    int* off = (int*)(p + o);         o = align_up(o + (size_t)(NN + 1) * 4, 512);
    int* bsums = (int*)(p + o);       o = align_up(o + 512, 512);
    int2* csr = (int2*)(p + o);       o = align_up(o + (size_t)NE * 8, 512);
    (void)ws_size; (void)in_sizes; (void)n_in; (void)out_size;

    float* hbuf[2] = {h0, h1};

    const int GRID_E = (NE + 255) / 256;          // 1563
    const int GRID_SCAN1 = (NN + 1023) / 1024;    // 98
    const int GRID_N256 = (NN + 255) / 256;       // 391
    const int GRID_ND = (size_t)NN * DD / 256;    // 50000
    const int GRID_LAYER = (NN + 63) / 64;        // 1563
    const int GRID_POOL = (NN + 63) / 64;         // 1563

    // zero deg + cursor (ws is poisoned 0xAA each call)
    hipMemsetAsync(deg, 0, (size_t)NN * 4, stream);
    hipMemsetAsync(cursor, 0, (size_t)NN * 4, stream);
    hipMemsetAsync(out, 0, (size_t)NG * DD * 4, stream);

    deg_kernel<<<GRID_E, 256, 0, stream>>>(ei, deg);
    scan1_kernel<<<GRID_SCAN1, 256, 0, stream>>>(deg, off, bsums);
    scan2_kernel<<<1, 128, 0, stream>>>(bsums, GRID_SCAN1);
    finish_kernel<<<GRID_N256, 256, 0, stream>>>(off, bsums, deg, dinv);
    fill_kernel<<<GRID_E, 256, 0, stream>>>(ei, off, cursor, csr, dinv);

    expand_kernel<<<GRID_ND, 256, 0, stream>>>(x, We, be, h0);

    for (int l = 0; l < NL; ++l) {
        const float* hin = hbuf[l & 1];
        float* hout = hbuf[(l & 1) ^ 1];
        layer_kernel<<<GRID_LAYER, 256, 0, stream>>>(hin, hout, off, csr, dinv,
                                                     Wg + (size_t)l * DD * DD,
                                                     bg + (size_t)l * DD);
    }

    pool_kernel<<<GRID_POOL, 128, 0, stream>>>(hbuf[NL & 1], bat, out);
}